// Round 6
// baseline (123.049 us; speedup 1.0000x reference)
//
#include <hip/hip_runtime.h>
#include <hip/hip_bf16.h>

typedef __bf16 bf16;
typedef bf16 bf16x8 __attribute__((ext_vector_type(8)));
typedef bf16 bf16x4 __attribute__((ext_vector_type(4)));
typedef float f32x4 __attribute__((ext_vector_type(4)));
typedef unsigned int u32;
typedef u32 u32x4 __attribute__((ext_vector_type(4)));

__device__ __forceinline__ f32x4 mfma16(bf16x8 a, bf16x8 b, f32x4 c) {
  return __builtin_amdgcn_mfma_f32_16x16x32_bf16(a, b, c, 0, 0, 0);
}

typedef __attribute__((address_space(3))) void lds_void;
typedef __attribute__((address_space(1))) void g_void;
__device__ __forceinline__ void gload_lds16(const bf16* g, void* l) {
  __builtin_amdgcn_global_load_lds((const g_void*)g, (lds_void*)l, 16, 0, 0);
}

__device__ __forceinline__ u32 pkbf(float a, float b) {
  unsigned short ua = __builtin_bit_cast(unsigned short, (bf16)a);
  unsigned short ub = __builtin_bit_cast(unsigned short, (bf16)b);
  return ((u32)ub << 16) | ua;
}

// ---------------- convert fp32 -> bf16 (x + weights) ----------------
__global__ __launch_bounds__(256) void convert_kernel(
    const float4* __restrict__ x, const float4* __restrict__ wq,
    const float4* __restrict__ wk, const float4* __restrict__ wv,
    const float4* __restrict__ w1, const float4* __restrict__ w2,
    bf16x4* __restrict__ xb, bf16x4* __restrict__ wqkvb,
    bf16x4* __restrict__ w1b, bf16x4* __restrict__ w2b)
{
  int t = blockIdx.x * 256 + threadIdx.x;
  const int NX = 4096 * 512 / 4;   // 524288
  const int NW = 512 * 512 / 4;    // 65536
  const float4* s; bf16x4* d; int o;
  if (t < NX)            { s = x;  d = xb;            o = t; }
  else if (t < NX+NW)    { s = wq; d = wqkvb;         o = t - NX; }
  else if (t < NX+2*NW)  { s = wk; d = wqkvb + NW;    o = t - NX - NW; }
  else if (t < NX+3*NW)  { s = wv; d = wqkvb + 2*NW;  o = t - NX - 2*NW; }
  else if (t < NX+4*NW)  { s = w1; d = w1b;           o = t - NX - 3*NW; }
  else                   { s = w2; d = w2b;           o = t - NX - 4*NW; }
  float4 v = s[o];
  bf16x4 r;
  r[0] = (bf16)v.x; r[1] = (bf16)v.y; r[2] = (bf16)v.z; r[3] = (bf16)v.w;
  d[o] = r;
}

// ---------------- LDS-staged GEMM: C = A(MxK) * B(NxK)^T, K=512 ----------------
template<int EPI, int BM, int BN, int WM_CNT, int WN_CNT>
__global__ __launch_bounds__(256) void gemm_lds(
    const bf16* __restrict__ A, const bf16* __restrict__ B,
    const float* __restrict__ bias, const float* __restrict__ xres,
    bf16* __restrict__ out, bf16* __restrict__ qb,
    bf16* __restrict__ kb, bf16* __restrict__ vb)
{
  constexpr int K = 512, BK = 32;
  constexpr int WT_M = BM / WM_CNT, WT_N = BN / WN_CNT;
  constexpr int MT = WT_M / 16, NT = WT_N / 16;
  constexpr int AI = BM / 16, BI = BN / 16, TI = AI + BI;
  __shared__ __align__(16) bf16 lA[BM][BK];
  __shared__ __align__(16) bf16 lB[BN][BK];

  const int lane = threadIdx.x & 63, w = threadIdx.x >> 6;
  const int lo = lane & 15, hi = lane >> 4;
  const int r4 = lane >> 2, q4 = lane & 3;
  const int wm = (w / WN_CNT) * WT_M, wn = (w % WN_CNT) * WT_N;
  const int m0 = blockIdx.y * BM, n0 = blockIdx.x * BN;

  f32x4 acc[MT][NT] = {};

  for (int kk = 0; kk < K; kk += BK) {
    __syncthreads();
#pragma unroll
    for (int inst = w; inst < TI; inst += 4) {
      if (inst < AI) {
        const bf16* g = A + (size_t)(m0 + inst * 16 + r4) * K + kk + q4 * 8;
        gload_lds16(g, ((char*)&lA[0][0]) + inst * 1024);
      } else {
        int bi = inst - AI;
        const bf16* g = B + (size_t)(n0 + bi * 16 + r4) * K + kk + q4 * 8;
        gload_lds16(g, ((char*)&lB[0][0]) + bi * 1024);
      }
    }
    __syncthreads();

    bf16x8 af[MT], bfr[NT];
#pragma unroll
    for (int mt = 0; mt < MT; ++mt)
      af[mt] = *(const bf16x8*)&lA[wm + mt * 16 + lo][hi * 8];
#pragma unroll
    for (int nt = 0; nt < NT; ++nt)
      bfr[nt] = *(const bf16x8*)&lB[wn + nt * 16 + lo][hi * 8];
#pragma unroll
    for (int mt = 0; mt < MT; ++mt)
#pragma unroll
      for (int nt = 0; nt < NT; ++nt)
        acc[mt][nt] = mfma16(af[mt], bfr[nt], acc[mt][nt]);
  }

#pragma unroll
  for (int mt = 0; mt < MT; ++mt) {
#pragma unroll
    for (int nt = 0; nt < NT; ++nt) {
#pragma unroll
      for (int r = 0; r < 4; ++r) {
        int m = m0 + wm + mt * 16 + hi * 4 + r;
        int n = n0 + wn + nt * 16 + lo;
        float v = acc[mt][nt][r];
        if (EPI == 0) {
          int p = n >> 9, h7 = (n >> 6) & 7, d = n & 63;
          int bb = m >> 10, i = m & 1023;
          size_t idx = ((size_t)(bb * 8 + h7) * 1024 + i) * 64 + d;
          bf16* dst = (p == 0) ? qb : (p == 1) ? kb : vb;
          dst[idx] = (bf16)v;
        } else if (EPI == 1) {
          float t = v + bias[n];
          out[(size_t)m * 512 + n] = (bf16)(t > 0.f ? t : 0.f);
        } else {
          out[(size_t)m * 512 + n] = (bf16)(v + bias[n] + xres[(size_t)m * 512 + n]);
        }
      }
    }
  }
}

// ---------------- Q transpose: Qb[bh][i][64] -> Qt[bh][d][1024] ----------------
__global__ __launch_bounds__(256) void transpose_q(
    const bf16* __restrict__ Qb, bf16* __restrict__ Qt)
{
  __shared__ __align__(16) bf16 t[64][72];
  const int ib = blockIdx.x, bh = blockIdx.y;
  const bf16* src = Qb + (size_t)bh * 65536 + (size_t)ib * 64 * 64;
  int r = threadIdx.x >> 2, cseg = (threadIdx.x & 3) * 16;
  bf16x8 a = *(const bf16x8*)(src + r * 64 + cseg);
  bf16x8 b = *(const bf16x8*)(src + r * 64 + cseg + 8);
  *(bf16x8*)&t[r][cseg] = a;
  *(bf16x8*)&t[r][cseg + 8] = b;
  __syncthreads();
  int d = threadIdx.x >> 2, iseg = (threadIdx.x & 3) * 16;
  bf16x8 o0, o1;
#pragma unroll
  for (int jj = 0; jj < 8; ++jj) {
    o0[jj] = t[iseg + jj][d];
    o1[jj] = t[iseg + 8 + jj][d];
  }
  bf16* dst = Qt + ((size_t)bh * 64 + d) * 1024 + ib * 64 + iseg;
  *(bf16x8*)dst = o0;
  *(bf16x8*)(dst + 8) = o1;
}

// ---------------- flash attention v5: no-max softmax + split-j partials --------
// jz in 0..3 each covers 256 j's. Partials are linearly combinable because the
// softmax max is fixed at 0: O = sum_jz O_jz / sum_jz l_jz.
template<bool PRE>
__device__ __forceinline__ void attn_step(
    int j0, int jn, const bf16* Vbase, const bf16* Qbase,
    bf16x8 (&vc)[4][2], bf16x8 (&vn)[4][2],
    bf16x8 kf0, bf16x8 kf1, u32* __restrict__ Pw,
    f32x4 (&o)[4], float (&ls)[4], int lo, int hi)
{
  // Q fragments for this j-tile (issued early; consumed at the PV mfma)
  bf16x8 qf[4][2];
#pragma unroll
  for (int et = 0; et < 4; ++et) {
    const bf16* qp = Qbase + (size_t)(et * 16 + lo) * 1024 + j0;
    qf[et][0] = *(const bf16x8*)(qp + hi * 8);
    qf[et][1] = *(const bf16x8*)(qp + 32 + hi * 8);
  }

  // S^T tiles: lane (lo,hi) holds S[i=lo][j=j0+16jt+4hi+r]
  f32x4 st[4];
#pragma unroll
  for (int jt = 0; jt < 4; ++jt) {
    f32x4 z = {};
    z = mfma16(vc[jt][0], kf0, z);
    st[jt] = mfma16(vc[jt][1], kf1, z);
  }

  // prefetch next V tile
  if (PRE) {
#pragma unroll
    for (int jt = 0; jt < 4; ++jt) {
      const bf16* vp = Vbase + (size_t)(jn + jt * 16 + lo) * 64;
      vn[jt][0] = *(const bf16x8*)(vp + hi * 8);
      vn[jt][1] = *(const bf16x8*)(vp + 32 + hi * 8);
    }
  }

  // p = exp(S) with fixed max 0; per-lane partial sums (reduced once at end)
  float p[4][4];
#pragma unroll
  for (int jt = 0; jt < 4; ++jt) {
    float s0 = 0.f, s1 = 0.f;
#pragma unroll
    for (int r = 0; r < 4; ++r) {
      p[jt][r] = __expf(st[jt][r]);
      if (r & 1) s1 += p[jt][r]; else s0 += p[jt][r];
    }
    ls[jt] += s0 + s1;
  }

  // pair-pack and transpose i<->j through wave-private LDS (stride 17 dw)
#pragma unroll
  for (int jt = 0; jt < 4; ++jt)
#pragma unroll
    for (int u = 0; u < 2; ++u)
      Pw[(8 * jt + 2 * hi + u) * 17 + lo] = pkbf(p[jt][2 * u], p[jt][2 * u + 1]);

  bf16x8 pa[2];
#pragma unroll
  for (int c = 0; c < 2; ++c) {
    u32x4 a4;
#pragma unroll
    for (int d = 0; d < 4; ++d) a4[d] = Pw[(16 * c + 4 * hi + d) * 17 + lo];
    pa[c] = __builtin_bit_cast(bf16x8, a4);
  }

  // PV: out[i][e] += P[i][j] * Q[j][e]
#pragma unroll
  for (int et = 0; et < 4; ++et) {
    o[et] = mfma16(pa[0], qf[et][0], o[et]);
    o[et] = mfma16(pa[1], qf[et][1], o[et]);
  }
}

__global__ __launch_bounds__(256, 4) void attn_kernel(
    const bf16* __restrict__ Kb, const bf16* __restrict__ Vb,
    const bf16* __restrict__ Qt,
    bf16* __restrict__ Pl0, bf16* __restrict__ Pl1,
    bf16* __restrict__ Pl2, bf16* __restrict__ Pl3,
    float* __restrict__ Ps)
{
  const int lane = threadIdx.x & 63;
  const int w    = threadIdx.x >> 6;
  const int lo = lane & 15, hi = lane >> 4;
  const int ib = blockIdx.x >> 2, jz = blockIdx.x & 3;
  const int h = blockIdx.y, b = blockIdx.z;
  const int bh = b * 8 + h;
  const int jbase = jz * 256;

  const bf16* Kbase = Kb + (size_t)bh * 65536;
  const bf16* Vbase = Vb + (size_t)bh * 65536;
  const bf16* Qbase = Qt + (size_t)bh * 65536;
  const int i0 = ib * 64 + w * 16;

  // K fragment (B-operand of S^T): lane (lo,hi) = K[i0+lo][8hi..], [32+8hi..]
  bf16x8 kf0 = *(const bf16x8*)(Kbase + (size_t)(i0 + lo) * 64 + hi * 8);
  bf16x8 kf1 = *(const bf16x8*)(Kbase + (size_t)(i0 + lo) * 64 + 32 + hi * 8);

  f32x4 o[4] = {};
  float ls[4] = {0.f, 0.f, 0.f, 0.f};

  __shared__ u32 Pt[2][4][544];   // [dbuf][wave][32 rows x 17 dw]
  u32* Pw0 = &Pt[0][w][0];
  u32* Pw1 = &Pt[1][w][0];

  bf16x8 vA[4][2], vB[4][2];
#pragma unroll
  for (int jt = 0; jt < 4; ++jt) {
    const bf16* vp = Vbase + (size_t)(jbase + jt * 16 + lo) * 64;
    vA[jt][0] = *(const bf16x8*)(vp + hi * 8);
    vA[jt][1] = *(const bf16x8*)(vp + 32 + hi * 8);
  }

  attn_step<true >(jbase,       jbase +  64, Vbase, Qbase, vA, vB, kf0, kf1, Pw0, o, ls, lo, hi);
  attn_step<true >(jbase +  64, jbase + 128, Vbase, Qbase, vB, vA, kf0, kf1, Pw1, o, ls, lo, hi);
  attn_step<true >(jbase + 128, jbase + 192, Vbase, Qbase, vA, vB, kf0, kf1, Pw0, o, ls, lo, hi);
  attn_step<false>(jbase + 192, jbase + 192, Vbase, Qbase, vB, vA, kf0, kf1, Pw1, o, ls, lo, hi);

  // partial row sums: after 2 shfl, every lane holds the sum for row i0+lo
  float lsum = (ls[0] + ls[1]) + (ls[2] + ls[3]);
  lsum += __shfl_xor(lsum, 16);
  lsum += __shfl_xor(lsum, 32);
  if (hi == 0)
    Ps[(size_t)jz * 32768 + ((size_t)b * 1024 + i0 + lo) * 8 + h] = lsum;

  bf16* Pl = (jz == 0) ? Pl0 : (jz == 1) ? Pl1 : (jz == 2) ? Pl2 : Pl3;
#pragma unroll
  for (int r = 0; r < 4; ++r) {
    int row = i0 + 4 * hi + r;
#pragma unroll
    for (int et = 0; et < 4; ++et) {
      int col = h * 64 + et * 16 + lo;
      Pl[((size_t)b * 1024 + row) * 512 + col] = (bf16)o[et][r];
    }
  }
}

// ---------------- combine split-j partials: Xn = sum Pl / sum Ps --------------
// NOTE: Xn aliases Pl0 (same flat layout) — each thread reads its 4 elements
// from all planes before writing the same addresses. No __restrict here.
__global__ __launch_bounds__(256) void attn_combine(
    const bf16* Pl0, const bf16* Pl1, const bf16* Pl2, const bf16* Pl3,
    const float* Ps, bf16* Xn)
{
  int t = blockIdx.x * 256 + threadIdx.x;
  int idx4 = t * 4;                    // [0, 2097152)
  int rowg = idx4 >> 9;                // global row 0..4095
  int h = (idx4 >> 6) & 7;
  const float* ps = Ps + (size_t)rowg * 8 + h;
  float inv = 1.0f / (ps[0] + ps[32768] + ps[65536] + ps[98304]);
  bf16x4 v0 = *(const bf16x4*)(Pl0 + idx4);
  bf16x4 v1 = *(const bf16x4*)(Pl1 + idx4);
  bf16x4 v2 = *(const bf16x4*)(Pl2 + idx4);
  bf16x4 v3 = *(const bf16x4*)(Pl3 + idx4);
  bf16x4 r;
#pragma unroll
  for (int k = 0; k < 4; ++k) {
    float s = ((float)v0[k] + (float)v1[k]) + ((float)v2[k] + (float)v3[k]);
    r[k] = (bf16)(s * inv);
  }
  *(bf16x4*)(Xn + idx4) = r;
}

// ---------------- rowwise LayerNorm: fp32 out ----------------
__global__ __launch_bounds__(256) void ln_kernel(
    const bf16* __restrict__ Yb, const float* __restrict__ lnw,
    const float* __restrict__ lnb, float* __restrict__ out)
{
  const int w = threadIdx.x >> 6, lane = threadIdx.x & 63;
  const int row = blockIdx.x * 4 + w;
  const bf16* yrow = Yb + (size_t)row * 512;
  bf16x8 yv = *(const bf16x8*)(yrow + lane * 8);
  float f[8], s = 0.f, s2 = 0.f;
#pragma unroll
  for (int j = 0; j < 8; ++j) { f[j] = (float)yv[j]; s += f[j]; s2 += f[j] * f[j]; }
#pragma unroll
  for (int off = 1; off < 64; off <<= 1) { s += __shfl_xor(s, off); s2 += __shfl_xor(s2, off); }
  float mean = s * (1.f / 512.f);
  float var  = s2 * (1.f / 512.f) - mean * mean;
  float rstd = rsqrtf(var + 1e-5f);
  int c = lane * 8;
  float o[8];
#pragma unroll
  for (int j = 0; j < 8; ++j) o[j] = (f[j] - mean) * rstd * lnw[c + j] + lnb[c + j];
  float* op = out + (size_t)row * 512 + c;
  *(float4*)(op)     = make_float4(o[0], o[1], o[2], o[3]);
  *(float4*)(op + 4) = make_float4(o[4], o[5], o[6], o[7]);
}

// ---------------- launch ----------------
extern "C" void kernel_launch(void* const* d_in, const int* in_sizes, int n_in,
                              void* d_out, int out_size, void* d_ws, size_t ws_size,
                              hipStream_t stream)
{
  const float* x   = (const float*)d_in[0];
  // d_in[1] = mask: all-true in this problem -> no-op, not read
  const float* Wq  = (const float*)d_in[2];
  const float* Wk  = (const float*)d_in[3];
  const float* Wv  = (const float*)d_in[4];
  const float* W1  = (const float*)d_in[5];
  const float* b1  = (const float*)d_in[6];
  const float* W2  = (const float*)d_in[7];
  const float* b2  = (const float*)d_in[8];
  const float* lnw = (const float*)d_in[9];
  const float* lnb = (const float*)d_in[10];
  float* out = (float*)d_out;
  char* ws = (char*)d_ws;

  bf16* Xb    = (bf16*)(ws + 0);          // 4 MB  bf16 X; dead after gemm0 -> plane0 -> Xn
  bf16* Wqkvb = (bf16*)(ws + 4194304);    // 1.5 MB
  bf16* W1b   = (bf16*)(ws + 5767168);    // 0.5 MB
  bf16* W2b   = (bf16*)(ws + 6291456);    // 0.5 MB
  bf16* Qb    = (bf16*)(ws + 6815744);    // 4 MB [bh][i][d]; dead after transpose -> plane1 -> H1
  bf16* Kb    = (bf16*)(ws + 11010048);   // 4 MB [bh][i][d] (reused as Y)
  bf16* Vb    = (bf16*)(ws + 15204352);   // 4 MB [bh][j][d]
  bf16* Qt    = (bf16*)(ws + 19398656);   // 4 MB [bh][d][i]
  bf16* Pl2   = (bf16*)(ws + 23592960);   // 4 MB partial plane 2
  bf16* Pl3   = (bf16*)(ws + 27787264);   // 4 MB partial plane 3
  float* Ps   = (float*)(ws + 31981568);  // 512 KB partial sums [4][4096][8]
  bf16* Pl0   = Xb;
  bf16* Pl1   = Qb;
  bf16* Xnb   = Xb;
  bf16* H1b   = Qb;
  bf16* Yb    = Kb;

  convert_kernel<<<3328, 256, 0, stream>>>(
      (const float4*)x, (const float4*)Wq, (const float4*)Wk, (const float4*)Wv,
      (const float4*)W1, (const float4*)W2,
      (bf16x4*)Xb, (bf16x4*)Wqkvb, (bf16x4*)W1b, (bf16x4*)W2b);

  gemm_lds<0, 64, 128, 2, 2><<<dim3(12, 64), 256, 0, stream>>>(
      Xb, Wqkvb, nullptr, nullptr, nullptr, Qb, Kb, Vb);

  transpose_q<<<dim3(16, 32), 256, 0, stream>>>(Qb, Qt);

  attn_kernel<<<dim3(64, 8, 4), 256, 0, stream>>>(Kb, Vb, Qt, Pl0, Pl1, Pl2, Pl3, Ps);

  attn_combine<<<2048, 256, 0, stream>>>(Pl0, Pl1, Pl2, Pl3, Ps, Xnb);

  gemm_lds<1, 32, 64, 2, 2><<<dim3(8, 128), 256, 0, stream>>>(
      Xnb, W1b, b1, nullptr, H1b, nullptr, nullptr, nullptr);

  gemm_lds<2, 32, 64, 2, 2><<<dim3(8, 128), 256, 0, stream>>>(
      H1b, W2b, b2, x, Yb, nullptr, nullptr, nullptr);

  ln_kernel<<<1024, 256, 0, stream>>>(Yb, lnw, lnb, out);
}

// Round 7
// 78.066 us; speedup vs baseline: 1.5762x; 1.5762x over previous
//
#include <hip/hip_runtime.h>
#include <hip/hip_bf16.h>

typedef __bf16 bf16;
typedef bf16 bf16x8 __attribute__((ext_vector_type(8)));
typedef bf16 bf16x4 __attribute__((ext_vector_type(4)));
typedef float f32x4 __attribute__((ext_vector_type(4)));
typedef unsigned int u32;
typedef u32 u32x4 __attribute__((ext_vector_type(4)));

__device__ __forceinline__ f32x4 mfma16(bf16x8 a, bf16x8 b, f32x4 c) {
  return __builtin_amdgcn_mfma_f32_16x16x32_bf16(a, b, c, 0, 0, 0);
}

typedef __attribute__((address_space(3))) void lds_void;
typedef __attribute__((address_space(1))) void g_void;
__device__ __forceinline__ void gload_lds16(const bf16* g, void* l) {
  __builtin_amdgcn_global_load_lds((const g_void*)g, (lds_void*)l, 16, 0, 0);
}

__device__ __forceinline__ u32 pkbf(float a, float b) {
  unsigned short ua = __builtin_bit_cast(unsigned short, (bf16)a);
  unsigned short ub = __builtin_bit_cast(unsigned short, (bf16)b);
  return ((u32)ub << 16) | ua;
}

// ---------------- convert fp32 -> bf16 (x + weights) ----------------
__global__ __launch_bounds__(256) void convert_kernel(
    const float4* __restrict__ x, const float4* __restrict__ wq,
    const float4* __restrict__ wk, const float4* __restrict__ wv,
    const float4* __restrict__ w1, const float4* __restrict__ w2,
    bf16x4* __restrict__ xb, bf16x4* __restrict__ wqkvb,
    bf16x4* __restrict__ w1b, bf16x4* __restrict__ w2b)
{
  int t = blockIdx.x * 256 + threadIdx.x;
  const int NX = 4096 * 512 / 4;   // 524288
  const int NW = 512 * 512 / 4;    // 65536
  const float4* s; bf16x4* d; int o;
  if (t < NX)            { s = x;  d = xb;            o = t; }
  else if (t < NX+NW)    { s = wq; d = wqkvb;         o = t - NX; }
  else if (t < NX+2*NW)  { s = wk; d = wqkvb + NW;    o = t - NX - NW; }
  else if (t < NX+3*NW)  { s = wv; d = wqkvb + 2*NW;  o = t - NX - 2*NW; }
  else if (t < NX+4*NW)  { s = w1; d = w1b;           o = t - NX - 3*NW; }
  else                   { s = w2; d = w2b;           o = t - NX - 4*NW; }
  float4 v = s[o];
  bf16x4 r;
  r[0] = (bf16)v.x; r[1] = (bf16)v.y; r[2] = (bf16)v.z; r[3] = (bf16)v.w;
  d[o] = r;
}

// ---------------- LDS-staged GEMM: C = A(MxK) * B(NxK)^T, K=512 ----------------
template<int EPI, int BM, int BN, int WM_CNT, int WN_CNT>
__global__ __launch_bounds__(256) void gemm_lds(
    const bf16* __restrict__ A, const bf16* __restrict__ B,
    const float* __restrict__ bias, const float* __restrict__ xres,
    bf16* __restrict__ out, bf16* __restrict__ qb,
    bf16* __restrict__ kb, bf16* __restrict__ vb)
{
  constexpr int K = 512, BK = 32;
  constexpr int WT_M = BM / WM_CNT, WT_N = BN / WN_CNT;
  constexpr int MT = WT_M / 16, NT = WT_N / 16;
  constexpr int AI = BM / 16, BI = BN / 16, TI = AI + BI;
  __shared__ __align__(16) bf16 lA[BM][BK];
  __shared__ __align__(16) bf16 lB[BN][BK];

  const int lane = threadIdx.x & 63, w = threadIdx.x >> 6;
  const int lo = lane & 15, hi = lane >> 4;
  const int r4 = lane >> 2, q4 = lane & 3;
  const int wm = (w / WN_CNT) * WT_M, wn = (w % WN_CNT) * WT_N;
  const int m0 = blockIdx.y * BM, n0 = blockIdx.x * BN;

  f32x4 acc[MT][NT] = {};

  for (int kk = 0; kk < K; kk += BK) {
    __syncthreads();
#pragma unroll
    for (int inst = w; inst < TI; inst += 4) {
      if (inst < AI) {
        const bf16* g = A + (size_t)(m0 + inst * 16 + r4) * K + kk + q4 * 8;
        gload_lds16(g, ((char*)&lA[0][0]) + inst * 1024);
      } else {
        int bi = inst - AI;
        const bf16* g = B + (size_t)(n0 + bi * 16 + r4) * K + kk + q4 * 8;
        gload_lds16(g, ((char*)&lB[0][0]) + bi * 1024);
      }
    }
    __syncthreads();

    bf16x8 af[MT], bfr[NT];
#pragma unroll
    for (int mt = 0; mt < MT; ++mt)
      af[mt] = *(const bf16x8*)&lA[wm + mt * 16 + lo][hi * 8];
#pragma unroll
    for (int nt = 0; nt < NT; ++nt)
      bfr[nt] = *(const bf16x8*)&lB[wn + nt * 16 + lo][hi * 8];
#pragma unroll
    for (int mt = 0; mt < MT; ++mt)
#pragma unroll
      for (int nt = 0; nt < NT; ++nt)
        acc[mt][nt] = mfma16(af[mt], bfr[nt], acc[mt][nt]);
  }

#pragma unroll
  for (int mt = 0; mt < MT; ++mt) {
#pragma unroll
    for (int nt = 0; nt < NT; ++nt) {
#pragma unroll
      for (int r = 0; r < 4; ++r) {
        int m = m0 + wm + mt * 16 + hi * 4 + r;
        int n = n0 + wn + nt * 16 + lo;
        float v = acc[mt][nt][r];
        if (EPI == 0) {
          int p = n >> 9, h7 = (n >> 6) & 7, d = n & 63;
          int bb = m >> 10, i = m & 1023;
          size_t idx = ((size_t)(bb * 8 + h7) * 1024 + i) * 64 + d;
          bf16* dst = (p == 0) ? qb : (p == 1) ? kb : vb;
          dst[idx] = (bf16)v;
        } else if (EPI == 1) {
          float t = v + bias[n];
          out[(size_t)m * 512 + n] = (bf16)(t > 0.f ? t : 0.f);
        } else {
          out[(size_t)m * 512 + n] = (bf16)(v + bias[n] + xres[(size_t)m * 512 + n]);
        }
      }
    }
  }
}

// ---------------- Q transpose: Qb[bh][i][64] -> Qt[bh][d][1024] ----------------
__global__ __launch_bounds__(256) void transpose_q(
    const bf16* __restrict__ Qb, bf16* __restrict__ Qt)
{
  __shared__ __align__(16) bf16 t[64][72];
  const int ib = blockIdx.x, bh = blockIdx.y;
  const bf16* src = Qb + (size_t)bh * 65536 + (size_t)ib * 64 * 64;
  int r = threadIdx.x >> 2, cseg = (threadIdx.x & 3) * 16;
  bf16x8 a = *(const bf16x8*)(src + r * 64 + cseg);
  bf16x8 b = *(const bf16x8*)(src + r * 64 + cseg + 8);
  *(bf16x8*)&t[r][cseg] = a;
  *(bf16x8*)&t[r][cseg + 8] = b;
  __syncthreads();
  int d = threadIdx.x >> 2, iseg = (threadIdx.x & 3) * 16;
  bf16x8 o0, o1;
#pragma unroll
  for (int jj = 0; jj < 8; ++jj) {
    o0[jj] = t[iseg + jj][d];
    o1[jj] = t[iseg + 8 + jj][d];
  }
  bf16* dst = Qt + ((size_t)bh * 64 + d) * 1024 + ib * 64 + iseg;
  *(bf16x8*)dst = o0;
  *(bf16x8*)(dst + 8) = o1;
}

// ---------------- flash attention v6: LDS-staged V/Q tiles shared by 8 waves ---
// Block: 512 thr, i-tile 128 (wave w owns rows i0=ib*128+w*16), j-loop 16x64.
// Per step: stage V[64][64] + Q[64][64] (16KB) once per block via global_load_lds
// (double-buffered, 2-barrier loop). XOR-swizzle (c16 ^= row&7) applied on the
// GLOBAL SOURCE (linear LDS dest; rule: both-sides-or-neither) and on the read.
// Softmax: no-max (scores bounded ~|25| << 88), per-lane partial sums, one
// reduce at the end. P transposed i<->j via wave-private LDS (stride 17 dw).
__global__ __launch_bounds__(512) void attn_kernel(
    const bf16* __restrict__ Kb, const bf16* __restrict__ Vb,
    const bf16* __restrict__ Qt, bf16* __restrict__ Xn)
{
  const int tid  = threadIdx.x;
  const int lane = tid & 63;
  const int w    = tid >> 6;
  const int lo = lane & 15, hi = lane >> 4;
  const int ib = blockIdx.x, h = blockIdx.y, b = blockIdx.z;
  const int bh = b * 8 + h;

  const bf16* Kbase = Kb + (size_t)bh * 65536;
  const bf16* Vbase = Vb + (size_t)bh * 65536;
  const bf16* Qbase = Qt + (size_t)bh * 65536;
  const int i0 = ib * 128 + w * 16;

  __shared__ __align__(16) bf16 Vl[2][64][64];   // 8KB per buffer
  __shared__ __align__(16) bf16 Ql[2][64][64];   // 8KB per buffer
  __shared__ u32 Pt[8][544];                     // per-wave P transpose

  // K fragment (B-operand of S^T): lane (lo,hi) = K[i0+lo][8hi..], [32+8hi..]
  bf16x8 kf0 = *(const bf16x8*)(Kbase + (size_t)(i0 + lo) * 64 + hi * 8);
  bf16x8 kf1 = *(const bf16x8*)(Kbase + (size_t)(i0 + lo) * 64 + 32 + hi * 8);

  // staging: thread t -> row t>>3, 16B-chunk t&7; source column pre-swizzled
  const int srow = tid >> 3, sc16 = tid & 7;
  const int ssc  = sc16 ^ (srow & 7);

  f32x4 o[4] = {};
  float ls[4] = {0.f, 0.f, 0.f, 0.f};
  u32* Pw = &Pt[w][0];

  // prologue: stage tile 0
  gload_lds16(Vbase + (size_t)srow * 64 + ssc * 8, &Vl[0][srow][sc16 * 8]);
  gload_lds16(Qbase + (size_t)srow * 1024 + ssc * 8, &Ql[0][srow][sc16 * 8]);
  __syncthreads();

  int cur = 0;
  for (int step = 0; step < 16; ++step) {
    const int j0 = step * 64;
    if (step < 15) {
      const int jn = j0 + 64;
      gload_lds16(Vbase + (size_t)(jn + srow) * 64 + ssc * 8, &Vl[cur ^ 1][srow][sc16 * 8]);
      gload_lds16(Qbase + (size_t)srow * 1024 + jn + ssc * 8, &Ql[cur ^ 1][srow][sc16 * 8]);
    }

    // V/Q fragments from LDS (swizzled read); rows jt*16+lo
    bf16x8 vf[4][2], qf[4][2];
#pragma unroll
    for (int jt = 0; jt < 4; ++jt) {
#pragma unroll
      for (int c = 0; c < 2; ++c) {
        const int cp = ((c << 2) | hi) ^ (lo & 7);
        vf[jt][c] = *(const bf16x8*)&Vl[cur][jt * 16 + lo][cp * 8];
        qf[jt][c] = *(const bf16x8*)&Ql[cur][jt * 16 + lo][cp * 8];
      }
    }

    // S^T tiles: lane (lo,hi) holds S[i=lo][j=j0+16jt+4hi+r]
    f32x4 st[4];
#pragma unroll
    for (int jt = 0; jt < 4; ++jt) {
      f32x4 z = {};
      z = mfma16(vf[jt][0], kf0, z);
      st[jt] = mfma16(vf[jt][1], kf1, z);
    }

    // p = exp(S), per-lane partial sums
    float p[4][4];
#pragma unroll
    for (int jt = 0; jt < 4; ++jt) {
      float s0 = 0.f, s1 = 0.f;
#pragma unroll
      for (int r = 0; r < 4; ++r) {
        p[jt][r] = __expf(st[jt][r]);
        if (r & 1) s1 += p[jt][r]; else s0 += p[jt][r];
      }
      ls[jt] += s0 + s1;
    }

    // pair-pack and transpose i<->j through wave-private LDS (stride 17 dw)
#pragma unroll
    for (int jt = 0; jt < 4; ++jt)
#pragma unroll
      for (int u = 0; u < 2; ++u)
        Pw[(8 * jt + 2 * hi + u) * 17 + lo] = pkbf(p[jt][2 * u], p[jt][2 * u + 1]);

    bf16x8 pa[2];
#pragma unroll
    for (int c = 0; c < 2; ++c) {
      u32x4 a4;
#pragma unroll
      for (int d = 0; d < 4; ++d) a4[d] = Pw[(16 * c + 4 * hi + d) * 17 + lo];
      pa[c] = __builtin_bit_cast(bf16x8, a4);
    }

    // PV: out[i][e] += P[i][j] * Q[j][e]
#pragma unroll
    for (int et = 0; et < 4; ++et) {
      o[et] = mfma16(pa[0], qf[et][0], o[et]);
      o[et] = mfma16(pa[1], qf[et][1], o[et]);
    }

    __syncthreads();   // staged tile complete + all reads of cur done
    cur ^= 1;
  }

  // final: reduce per-lane partial sums (row i = lo) across the 4 hi-groups
  float lsum = (ls[0] + ls[1]) + (ls[2] + ls[3]);
  lsum += __shfl_xor(lsum, 16);
  lsum += __shfl_xor(lsum, 32);
  float rl = 1.0f / lsum;
#pragma unroll
  for (int r = 0; r < 4; ++r) {
    float rb = __shfl(rl, (hi << 2) | r);   // row 4hi+r lives at lane lo=4hi+r
    int row = i0 + 4 * hi + r;
#pragma unroll
    for (int et = 0; et < 4; ++et) {
      int col = h * 64 + et * 16 + lo;
      Xn[((size_t)b * 1024 + row) * 512 + col] = (bf16)(o[et][r] * rb);
    }
  }
}

// ---------------- rowwise LayerNorm: fp32 out ----------------
__global__ __launch_bounds__(256) void ln_kernel(
    const bf16* __restrict__ Yb, const float* __restrict__ lnw,
    const float* __restrict__ lnb, float* __restrict__ out)
{
  const int w = threadIdx.x >> 6, lane = threadIdx.x & 63;
  const int row = blockIdx.x * 4 + w;
  const bf16* yrow = Yb + (size_t)row * 512;
  bf16x8 yv = *(const bf16x8*)(yrow + lane * 8);
  float f[8], s = 0.f, s2 = 0.f;
#pragma unroll
  for (int j = 0; j < 8; ++j) { f[j] = (float)yv[j]; s += f[j]; s2 += f[j] * f[j]; }
#pragma unroll
  for (int off = 1; off < 64; off <<= 1) { s += __shfl_xor(s, off); s2 += __shfl_xor(s2, off); }
  float mean = s * (1.f / 512.f);
  float var  = s2 * (1.f / 512.f) - mean * mean;
  float rstd = rsqrtf(var + 1e-5f);
  int c = lane * 8;
  float o[8];
#pragma unroll
  for (int j = 0; j < 8; ++j) o[j] = (f[j] - mean) * rstd * lnw[c + j] + lnb[c + j];
  float* op = out + (size_t)row * 512 + c;
  *(float4*)(op)     = make_float4(o[0], o[1], o[2], o[3]);
  *(float4*)(op + 4) = make_float4(o[4], o[5], o[6], o[7]);
}

// ---------------- launch ----------------
extern "C" void kernel_launch(void* const* d_in, const int* in_sizes, int n_in,
                              void* d_out, int out_size, void* d_ws, size_t ws_size,
                              hipStream_t stream)
{
  const float* x   = (const float*)d_in[0];
  // d_in[1] = mask: all-true in this problem -> no-op, not read
  const float* Wq  = (const float*)d_in[2];
  const float* Wk  = (const float*)d_in[3];
  const float* Wv  = (const float*)d_in[4];
  const float* W1  = (const float*)d_in[5];
  const float* b1  = (const float*)d_in[6];
  const float* W2  = (const float*)d_in[7];
  const float* b2  = (const float*)d_in[8];
  const float* lnw = (const float*)d_in[9];
  const float* lnb = (const float*)d_in[10];
  float* out = (float*)d_out;
  char* ws = (char*)d_ws;

  bf16* Xb    = (bf16*)(ws + 0);          // 4 MB  bf16 X (reused as Xnew after attn)
  bf16* Wqkvb = (bf16*)(ws + 4194304);    // 1.5 MB
  bf16* W1b   = (bf16*)(ws + 5767168);    // 0.5 MB
  bf16* W2b   = (bf16*)(ws + 6291456);    // 0.5 MB
  bf16* Qb    = (bf16*)(ws + 6815744);    // 4 MB [bh][i][d] (reused as H1)
  bf16* Kb    = (bf16*)(ws + 11010048);   // 4 MB [bh][i][d] (reused as Y)
  bf16* Vb    = (bf16*)(ws + 15204352);   // 4 MB [bh][j][d]
  bf16* Qt    = (bf16*)(ws + 19398656);   // 4 MB [bh][d][i]
  bf16* Xnb   = Xb;
  bf16* H1b   = Qb;
  bf16* Yb    = Kb;

  convert_kernel<<<3328, 256, 0, stream>>>(
      (const float4*)x, (const float4*)Wq, (const float4*)Wk, (const float4*)Wv,
      (const float4*)W1, (const float4*)W2,
      (bf16x4*)Xb, (bf16x4*)Wqkvb, (bf16x4*)W1b, (bf16x4*)W2b);

  gemm_lds<0, 64, 128, 2, 2><<<dim3(12, 64), 256, 0, stream>>>(
      Xb, Wqkvb, nullptr, nullptr, nullptr, Qb, Kb, Vb);

  transpose_q<<<dim3(16, 32), 256, 0, stream>>>(Qb, Qt);

  attn_kernel<<<dim3(8, 8, 4), 512, 0, stream>>>(Kb, Vb, Qt, Xnb);

  gemm_lds<1, 32, 64, 2, 2><<<dim3(8, 128), 256, 0, stream>>>(
      Xnb, W1b, b1, nullptr, H1b, nullptr, nullptr, nullptr);

  gemm_lds<2, 32, 64, 2, 2><<<dim3(8, 128), 256, 0, stream>>>(
      H1b, W2b, b2, x, Yb, nullptr, nullptr, nullptr);

  ln_kernel<<<1024, 256, 0, stream>>>(Yb, lnw, lnb, out);
}